// Round 6
// baseline (173.451 us; speedup 1.0000x reference)
//
#include <hip/hip_runtime.h>

// Chamfer loss: pred (2048,8,3) vs gt (2048,8,3) fp32. N=16384 pts/side.
// out = mean(min_m d) + mean(min_n d); 8-corner group-mean == global mean.
//
// R6: ONE kernel + one 4-byte-granular memset node (no cooperative launch --
// R5's hipLaunchCooperativeKernel silently failed: absmax == stub value).
//   memset: ws[0 .. 2N] = 0xFF  -> min-slots = 0xFFFFFFFF (+inf for uint-
//           ordered non-negative floats) AND ticket = 0xFFFFFFFF (known init).
//   kernel (1024 blocks, 4/CU):
//     phase 1: per-(x-block, y-seg) brute force, t = x.y - |y|^2/2 from LDS,
//              d2 = max(|x|^2 - 2*max t, 0), device-scope atomicMin on bits.
//              RPT=16 + y-pairs/max3: 112 VALU per 2 ds_read_b128 (R4 showed
//              RPT=8 makes the LDS pipe ~86% of VALU time; R2 showed 4.1
//              op/pair; this combines 3.5 op/pair with low LDS traffic).
//     ticket:  threadfence + atomicAdd; last arrival (old == GRID-2, exact
//              since init is 0xFFFFFFFF) reads the 128 KB mins with agent-
//              scope loads (XCD-safe), sqrt+sum, writes out[0]. No spinning,
//              no co-residency or dispatch-order assumption.
// Fallback (ws too small): R3's proven 3-kernel atomic path.

#define NPTS   16384
#define RPT    16             // x-points per thread
#define BLOCK  256
#define XPB    (RPT * BLOCK)  // 4096 x-points per block
#define NXB    (NPTS / XPB)   // 4 x-blocks
#define NSEG   128            // y segments -> 2*4*128 = 1024 blocks (4/CU)
#define YSEG   (NPTS / NSEG)  // 128 y-points per segment (one LDS chunk)
#define GRID   (2 * NXB * NSEG)
#define WS_NEED (2 * NPTS * 4 + 4)

__global__ __launch_bounds__(BLOCK, 4) void chamfer_fused(
        const float* __restrict__ pred, const float* __restrict__ gt,
        unsigned int* __restrict__ mins, unsigned int* __restrict__ ticket,
        float* __restrict__ out) {
    const int b   = blockIdx.x;
    const int dir = b >> 9;            // 512 blocks per direction
    const int xb  = (b >> 7) & (NXB - 1);
    const int ys  = b & (NSEG - 1);
    const float* __restrict__ X = dir ? gt : pred;
    const float* __restrict__ Y = dir ? pred : gt;
    unsigned int* __restrict__ outm = mins + dir * NPTS;
    const int tid = threadIdx.x;

    // ---- phase 1: brute-force mins over one y-segment ----
    __shared__ float4 sh[YSEG];  // (yx, yy, yz, -|y|^2/2)
    if (tid < YSEG) {
        int yi = ys * YSEG + tid;
        float a = Y[3 * yi + 0], bb = Y[3 * yi + 1], c = Y[3 * yi + 2];
        sh[tid] = make_float4(a, bb, c, -0.5f * (a * a + bb * bb + c * c));
    }

    float xx[RPT], xy[RPT], xz[RPT], x2[RPT], mx[RPT];
    const int xbase = xb * XPB;
#pragma unroll
    for (int r = 0; r < RPT; ++r) {
        int xi = xbase + r * BLOCK + tid;
        xx[r] = X[3 * xi + 0];
        xy[r] = X[3 * xi + 1];
        xz[r] = X[3 * xi + 2];
        x2[r] = xx[r] * xx[r] + xy[r] * xy[r] + xz[r] * xz[r];
        mx[r] = -3.0e38f;
    }

    __syncthreads();

    for (int j = 0; j < YSEG; j += 2) {
        float4 y0 = sh[j];      // uniform address -> broadcast, conflict-free
        float4 y1 = sh[j + 1];
#pragma unroll
        for (int r = 0; r < RPT; ++r) {
            float t0 = fmaf(xz[r], y0.z, y0.w);
            t0 = fmaf(xy[r], y0.y, t0);
            t0 = fmaf(xx[r], y0.x, t0);
            float t1 = fmaf(xz[r], y1.z, y1.w);
            t1 = fmaf(xy[r], y1.y, t1);
            t1 = fmaf(xx[r], y1.x, t1);
            mx[r] = fmaxf(mx[r], fmaxf(t0, t1));  // -> v_max3_f32
        }
    }

#pragma unroll
    for (int r = 0; r < RPT; ++r) {
        int xi = xbase + r * BLOCK + tid;
        float d2 = fmaxf(fmaf(-2.0f, mx[r], x2[r]), 0.0f);
        atomicMin(&outm[xi], __float_as_uint(d2));  // device scope by default
    }

    // ---- last-block final reduction ----
    __shared__ bool is_last;
    __threadfence();  // make this block's atomicMins globally ordered
    if (tid == 0) {
        unsigned int old = atomicAdd(ticket, 1u);
        // init = 0xFFFFFFFF (our memset): k-th arrival returns init + (k-1),
        // so the GRID-th (last) sees 0xFFFFFFFF + (GRID-1) = GRID - 2.
        is_last = (old == (unsigned int)(GRID - 2));
    }
    __syncthreads();

    if (is_last) {
        __threadfence();  // acquire: see all other blocks' mins
        float s = 0.0f;
        for (int i = tid; i < 2 * NPTS; i += BLOCK) {
            unsigned int u = __hip_atomic_load(&mins[i], __ATOMIC_RELAXED,
                                               __HIP_MEMORY_SCOPE_AGENT);
            s += sqrtf(__uint_as_float(u));
        }
#pragma unroll
        for (int off = 32; off > 0; off >>= 1)
            s += __shfl_down(s, off, 64);
        __shared__ float lsum[4];
        if ((tid & 63) == 0) lsum[tid >> 6] = s;
        __syncthreads();
        if (tid == 0)
            out[0] = (lsum[0] + lsum[1] + lsum[2] + lsum[3]) *
                     (1.0f / (float)NPTS);
    }
}

// ---------------- fallback path (small ws): R3 atomic version ----------------

__global__ __launch_bounds__(256) void init_mins(unsigned int* mins, float* out) {
    int i = blockIdx.x * blockDim.x + threadIdx.x;
    if (i < 2 * NPTS) mins[i] = 0x7F800000u;
    if (i == 0) out[0] = 0.0f;
}

__global__ __launch_bounds__(BLOCK, 4) void chamfer_min_atomic(
        const float* __restrict__ pred, const float* __restrict__ gt,
        unsigned int* __restrict__ mins) {
    const int xb  = blockIdx.x;
    const int ys  = blockIdx.y;
    const int dir = blockIdx.z;
    const float* __restrict__ X = dir ? gt : pred;
    const float* __restrict__ Y = dir ? pred : gt;
    unsigned int* __restrict__ outm = mins + dir * NPTS;
    const int tid = threadIdx.x;

    __shared__ float4 sh[YSEG];
    if (tid < YSEG) {
        int yi = ys * YSEG + tid;
        float a = Y[3 * yi + 0], b = Y[3 * yi + 1], c = Y[3 * yi + 2];
        sh[tid] = make_float4(a, b, c, -0.5f * (a * a + b * b + c * c));
    }
    float xx[RPT], xy[RPT], xz[RPT], x2[RPT], mx[RPT];
    const int xbase = xb * XPB;
#pragma unroll
    for (int r = 0; r < RPT; ++r) {
        int xi = xbase + r * BLOCK + tid;
        xx[r] = X[3 * xi + 0];
        xy[r] = X[3 * xi + 1];
        xz[r] = X[3 * xi + 2];
        x2[r] = xx[r] * xx[r] + xy[r] * xy[r] + xz[r] * xz[r];
        mx[r] = -3.0e38f;
    }
    __syncthreads();
    for (int j = 0; j < YSEG; j += 2) {
        float4 y0 = sh[j], y1 = sh[j + 1];
#pragma unroll
        for (int r = 0; r < RPT; ++r) {
            float t0 = fmaf(xz[r], y0.z, y0.w);
            t0 = fmaf(xy[r], y0.y, t0);
            t0 = fmaf(xx[r], y0.x, t0);
            float t1 = fmaf(xz[r], y1.z, y1.w);
            t1 = fmaf(xy[r], y1.y, t1);
            t1 = fmaf(xx[r], y1.x, t1);
            mx[r] = fmaxf(mx[r], fmaxf(t0, t1));
        }
    }
#pragma unroll
    for (int r = 0; r < RPT; ++r) {
        int xi = xbase + r * BLOCK + tid;
        float d2 = fmaxf(fmaf(-2.0f, mx[r], x2[r]), 0.0f);
        atomicMin(&outm[xi], __float_as_uint(d2));
    }
}

__global__ __launch_bounds__(256) void chamfer_reduce_atomic(
        const unsigned int* __restrict__ mins, float* __restrict__ out) {
    const int gid = blockIdx.x * 256 + threadIdx.x;
    float s = 0.0f;
#pragma unroll
    for (int i = 0; i < 2; ++i)
        s += sqrtf(__uint_as_float(mins[gid + i * 64 * 256]));
#pragma unroll
    for (int off = 32; off > 0; off >>= 1)
        s += __shfl_down(s, off, 64);
    if ((threadIdx.x & 63) == 0)
        atomicAdd(out, s * (1.0f / (float)NPTS));
}

extern "C" void kernel_launch(void* const* d_in, const int* in_sizes, int n_in,
                              void* d_out, int out_size, void* d_ws, size_t ws_size,
                              hipStream_t stream) {
    const float* pred = (const float*)d_in[0];
    const float* gt   = (const float*)d_in[1];
    float* out        = (float*)d_out;
    unsigned int* mins   = (unsigned int*)d_ws;        // 2*NPTS uints (128 KB)
    unsigned int* ticket = mins + 2 * NPTS;            // 1 uint

    if (ws_size >= (size_t)WS_NEED) {
        // mins -> 0xFFFFFFFF (+inf for uint-ordered d2 bits); ticket -> known init
        hipMemsetAsync(d_ws, 0xFF, (size_t)WS_NEED, stream);
        hipLaunchKernelGGL(chamfer_fused, dim3(GRID), dim3(BLOCK), 0, stream,
                           pred, gt, mins, ticket, out);
    } else {
        hipLaunchKernelGGL(init_mins, dim3((2 * NPTS + 255) / 256), dim3(256), 0,
                           stream, mins, out);
        hipLaunchKernelGGL(chamfer_min_atomic, dim3(NXB, NSEG, 2), dim3(BLOCK), 0,
                           stream, pred, gt, mins);
        hipLaunchKernelGGL(chamfer_reduce_atomic, dim3(64), dim3(256), 0, stream,
                           mins, out);
    }
}

// Round 7
// 103.253 us; speedup vs baseline: 1.6799x; 1.6799x over previous
//
#include <hip/hip_runtime.h>

// Chamfer loss: pred (2048,8,3) vs gt (2048,8,3) fp32. N=16384 pts/side.
// out = mean(min_m d) + mean(min_n d); 8-corner group-mean == global mean.
//
// R7: SHARED-T kernel. All rounds show ~45-50 us of fixed harness overhead
// (R6: 1 kernel+memset still had 45), so the lever is the main kernel.
// R2-R6 computed the dot matrix twice (once per direction). Here one pass
// computes t[n][m] = x.y - |y_m|^2/2 and feeds BOTH directions:
//   row (pred->gt):  rmx[r] = max_j t  -> d2 = |x|^2 - 2*rmx   (as before)
//   col (gt->pred):  u = t - |x_r|^2/2; M_j = max_{n} u
//                    d2_g[j] = |y|^2 - 2*max_n(x.y - |x|^2/2) - |y|^2 = -2*M_j
//   (|y|^2 cancels: d2_g = -2*M_j, clamped >= 0 BEFORE uint atomicMin.)
// Cost/pair-both-dirs: 3 fma + 0.5 row-max3 + 1 sub + 0.5 col-tree + ~0.3
// overhead ~= 5.3 vs 7.0 previously -> main ~48*5.3/7 ~= 36 us.
// Col partials: LDS chunk buffer [32 j][256 thr] (pad 257), reduced every
// 32 y by 8-thread slices + shfl_xor, 1 atomicMin per y per block.
// Nodes: memset(mins=0xFF) + memset(out=0) + main(8x128 blocks) + reduce(64).

#define NPTS   16384
#define RPT    8              // x-points per thread
#define BLOCK  256
#define XPB    (RPT * BLOCK)  // 2048 x per block
#define NXB    (NPTS / XPB)   // 8
#define NSEG   128            // y segments -> grid 8*128 = 1024 blocks
#define YSEG   (NPTS / NSEG)  // 128 y per block
#define CHUNK  32             // col-partial chunk (LDS rows)
#define CPAD   257            // padded stride (bank-conflict break)
#define WS_NEED (2 * NPTS * 4)

__global__ __launch_bounds__(BLOCK, 4) void chamfer_both(
        const float* __restrict__ pred, const float* __restrict__ gt,
        unsigned int* __restrict__ minp, unsigned int* __restrict__ ming) {
    const int xb  = blockIdx.x;   // x-block (pred side)
    const int ys  = blockIdx.y;   // y-segment (gt side)
    const int tid = threadIdx.x;

    __shared__ float4 shy[YSEG];               // (yx, yy, yz, -|y|^2/2)
    __shared__ float  shp[CHUNK * CPAD];       // col partials [j_local][tid]

    if (tid < YSEG) {
        int yi = ys * YSEG + tid;
        float a = gt[3 * yi + 0], b = gt[3 * yi + 1], c = gt[3 * yi + 2];
        shy[tid] = make_float4(a, b, c, -0.5f * (a * a + b * b + c * c));
    }

    float xx[RPT], xy[RPT], xz[RPT], x2[RPT], hv[RPT], rmx[RPT];
    const int xbase = xb * XPB;
#pragma unroll
    for (int r = 0; r < RPT; ++r) {
        int xi = xbase + r * BLOCK + tid;
        xx[r] = pred[3 * xi + 0];
        xy[r] = pred[3 * xi + 1];
        xz[r] = pred[3 * xi + 2];
        x2[r] = xx[r] * xx[r] + xy[r] * xy[r] + xz[r] * xz[r];
        hv[r] = 0.5f * x2[r];
        rmx[r] = -3.0e38f;
    }

    __syncthreads();

    for (int c = 0; c < YSEG; c += CHUNK) {
#pragma unroll 2
        for (int jj = 0; jj < CHUNK; jj += 2) {
            float4 y0 = shy[c + jj];       // broadcast, conflict-free
            float4 y1 = shy[c + jj + 1];
            float u0[RPT], u1[RPT];
#pragma unroll
            for (int r = 0; r < RPT; ++r) {
                float t0 = fmaf(xz[r], y0.z, y0.w);
                t0 = fmaf(xy[r], y0.y, t0);
                t0 = fmaf(xx[r], y0.x, t0);
                float t1 = fmaf(xz[r], y1.z, y1.w);
                t1 = fmaf(xy[r], y1.y, t1);
                t1 = fmaf(xx[r], y1.x, t1);
                rmx[r] = fmaxf(rmx[r], fmaxf(t0, t1));  // v_max3
                u0[r] = t0 - hv[r];
                u1[r] = t1 - hv[r];
            }
            // 8 -> 1 max trees (max3 peepholes: 2x max3 + fmax + max3)
            float g0 = fmaxf(fmaxf(fmaxf(u0[0], u0[1]), u0[2]),
                             fmaxf(fmaxf(u0[3], u0[4]), u0[5]));
            float cp0 = fmaxf(fmaxf(g0, u0[6]), u0[7]);
            float g1 = fmaxf(fmaxf(fmaxf(u1[0], u1[1]), u1[2]),
                             fmaxf(fmaxf(u1[3], u1[4]), u1[5]));
            float cp1 = fmaxf(fmaxf(g1, u1[6]), u1[7]);
            shp[(jj + 0) * CPAD + tid] = cp0;
            shp[(jj + 1) * CPAD + tid] = cp1;
        }
        __syncthreads();
        // chunk reduce: 8 threads per j (slice = tid&7), 32 strided reads each
        {
            const int jl = tid >> 3;       // 0..31
            const int sl = tid & 7;        // 0..7
            float m = -3.0e38f;
#pragma unroll 8
            for (int k = 0; k < 32; ++k)
                m = fmaxf(m, shp[jl * CPAD + sl + 8 * k]);
            m = fmaxf(m, __shfl_xor(m, 1, 64));
            m = fmaxf(m, __shfl_xor(m, 2, 64));
            m = fmaxf(m, __shfl_xor(m, 4, 64));
            if (sl == 0) {
                int yj = ys * YSEG + c + jl;
                float d2 = fmaxf(-2.0f * m, 0.0f);   // clamp BEFORE uint min
                atomicMin(&ming[yj], __float_as_uint(d2));
            }
        }
        __syncthreads();  // shp reused next chunk
    }

#pragma unroll
    for (int r = 0; r < RPT; ++r) {
        int xi = xbase + r * BLOCK + tid;
        float d2 = fmaxf(fmaf(-2.0f, rmx[r], x2[r]), 0.0f);
        atomicMin(&minp[xi], __float_as_uint(d2));
    }
}

__global__ __launch_bounds__(256) void chamfer_reduce(
        const unsigned int* __restrict__ mins, float* __restrict__ out) {
    const int gid = blockIdx.x * 256 + threadIdx.x;  // 64 blocks x 256
    float s = 0.0f;
#pragma unroll
    for (int i = 0; i < 2; ++i)
        s += sqrtf(__uint_as_float(mins[gid + i * 64 * 256]));
#pragma unroll
    for (int off = 32; off > 0; off >>= 1)
        s += __shfl_down(s, off, 64);
    if ((threadIdx.x & 63) == 0)
        atomicAdd(out, s * (1.0f / (float)NPTS));
}

// ---------------- fallback (tiny ws): R3 atomic path ----------------

__global__ __launch_bounds__(256) void init_mins(unsigned int* mins, float* out) {
    int i = blockIdx.x * blockDim.x + threadIdx.x;
    if (i < 2 * NPTS) mins[i] = 0x7F800000u;
    if (i == 0) out[0] = 0.0f;
}

__global__ __launch_bounds__(BLOCK, 4) void chamfer_min_atomic(
        const float* __restrict__ pred, const float* __restrict__ gt,
        unsigned int* __restrict__ mins) {
    const int xb  = blockIdx.x;
    const int ys  = blockIdx.y;
    const int dir = blockIdx.z;
    const float* __restrict__ X = dir ? gt : pred;
    const float* __restrict__ Y = dir ? pred : gt;
    unsigned int* __restrict__ outm = mins + dir * NPTS;
    const int tid = threadIdx.x;

    __shared__ float4 sh[YSEG];
    if (tid < YSEG) {
        int yi = ys * YSEG + tid;
        float a = Y[3 * yi + 0], b = Y[3 * yi + 1], c = Y[3 * yi + 2];
        sh[tid] = make_float4(a, b, c, -0.5f * (a * a + b * b + c * c));
    }
    float xx[RPT], xy[RPT], xz[RPT], x2[RPT], mx[RPT];
    const int xbase = xb * XPB;
#pragma unroll
    for (int r = 0; r < RPT; ++r) {
        int xi = xbase + r * BLOCK + tid;
        xx[r] = X[3 * xi + 0];
        xy[r] = X[3 * xi + 1];
        xz[r] = X[3 * xi + 2];
        x2[r] = xx[r] * xx[r] + xy[r] * xy[r] + xz[r] * xz[r];
        mx[r] = -3.0e38f;
    }
    __syncthreads();
#pragma unroll 2
    for (int j = 0; j < YSEG; j += 2) {
        float4 y0 = sh[j], y1 = sh[j + 1];
#pragma unroll
        for (int r = 0; r < RPT; ++r) {
            float t0 = fmaf(xz[r], y0.z, y0.w);
            t0 = fmaf(xy[r], y0.y, t0);
            t0 = fmaf(xx[r], y0.x, t0);
            float t1 = fmaf(xz[r], y1.z, y1.w);
            t1 = fmaf(xy[r], y1.y, t1);
            t1 = fmaf(xx[r], y1.x, t1);
            mx[r] = fmaxf(mx[r], fmaxf(t0, t1));
        }
    }
#pragma unroll
    for (int r = 0; r < RPT; ++r) {
        int xi = xbase + r * BLOCK + tid;
        float d2 = fmaxf(fmaf(-2.0f, mx[r], x2[r]), 0.0f);
        atomicMin(&outm[xi], __float_as_uint(d2));
    }
}

extern "C" void kernel_launch(void* const* d_in, const int* in_sizes, int n_in,
                              void* d_out, int out_size, void* d_ws, size_t ws_size,
                              hipStream_t stream) {
    const float* pred = (const float*)d_in[0];
    const float* gt   = (const float*)d_in[1];
    float* out        = (float*)d_out;
    unsigned int* minp = (unsigned int*)d_ws;   // [NPTS] pred->gt
    unsigned int* ming = minp + NPTS;           // [NPTS] gt->pred

    if (ws_size >= (size_t)WS_NEED) {
        hipMemsetAsync(d_ws, 0xFF, (size_t)WS_NEED, stream);  // mins = huge
        hipMemsetAsync(d_out, 0, sizeof(float), stream);       // out = 0
        hipLaunchKernelGGL(chamfer_both, dim3(NXB, NSEG), dim3(BLOCK), 0, stream,
                           pred, gt, minp, ming);
        hipLaunchKernelGGL(chamfer_reduce, dim3(64), dim3(256), 0, stream,
                           minp, out);
    } else {
        hipLaunchKernelGGL(init_mins, dim3((2 * NPTS + 255) / 256), dim3(256), 0,
                           stream, minp, out);
        hipLaunchKernelGGL(chamfer_min_atomic, dim3(NXB, NSEG, 2), dim3(BLOCK), 0,
                           stream, pred, gt, minp);
        hipLaunchKernelGGL(chamfer_reduce, dim3(64), dim3(256), 0, stream,
                           minp, out);
    }
}

// Round 8
// 102.078 us; speedup vs baseline: 1.6992x; 1.0115x over previous
//
#include <hip/hip_runtime.h>

// Chamfer loss: pred (2048,8,3) vs gt (2048,8,3) fp32. N=16384 pts/side.
// out = mean(min_m d) + mean(min_n d); 8-corner group-mean == global mean.
//
// R8: MFMA kernel. u[n][m] = x.y - |x|^2/2 - |y|^2/2 = -d^2/2, so
//   d2_p[n] = -2*max_m u,  d2_g[m] = -2*max_n u.
// One v_mfma_f32_32x32x16_bf16 computes a 32x32 u-tile with fp32-split
// precision, packing everything into K=16:
//   k0-2 : xh*yh   k3-5: xl*yh   k6-8: xh*yl   (x = xh + xl bf16 split)
//   k9-10: (-hx_hi,-hx_lo)*1     k11-12: 1*(-hy_hi,-hy_lo)   k13-15: 0
// (dropped xl*yl ~ 1e-5 -> d2 err ~3e-5, threshold 4e-3.)
// Layouts: C/D col=lane&31, row=(reg&3)+8*(reg>>2)+4*(lane>>5) [HW-verified];
// A/B: m(n)=lane&31, k=(lane>>5)*8+j (32x32 analog of verified 16x16 rule).
// Per 1024-pair tile: 1 ds_read_b128 (B frag, contiguous 16B/lane,
// conflict-free) + 1 MFMA + 16 rmx folds + 8-op max3 tree + 1 ds_min_u32.
// Row side: rmx[16] folded across the y-loop, shfl-reduced once per wave.
// Col side: LDS colbuf (uint d2 bits, >=0) flushed to global at block end.
// Grid: 128 x-groups (4 waves x 32 pts) x 16 y-segs (1024 pts) = 2048 blocks.

#define NPTS   16384
#define YS     1024            // y-points per block segment
#define NYS    (NPTS / YS)     // 16
#define NXG    (NPTS / 128)    // 128 block-groups (4 waves * 32 x each)
#define ONEBF  0x3F80u         // bf16 1.0
#define WS_NEED (2 * NPTS * 4)

typedef short  short8  __attribute__((ext_vector_type(8)));
typedef float  float16 __attribute__((ext_vector_type(16)));

union FragAB { unsigned short us[8]; uint4 u4; short8 s8; };
union FragC  { float16 v; float f[16]; };

__device__ __forceinline__ unsigned short bf_rne(float f) {
    unsigned int u = __float_as_uint(f);
    return (unsigned short)((u + 0x7FFFu + ((u >> 16) & 1u)) >> 16);
}
__device__ __forceinline__ float bf2f(unsigned short h) {
    return __uint_as_float(((unsigned int)h) << 16);
}

__global__ __launch_bounds__(256, 4) void chamfer_mfma(
        const float* __restrict__ pred, const float* __restrict__ gt,
        unsigned int* __restrict__ minp, unsigned int* __restrict__ ming) {
    __shared__ uint4 ybufA[YS];          // B-frag dwords, q=0 half
    __shared__ uint4 ybufB[YS];          // B-frag dwords, q=1 half
    __shared__ unsigned int colbuf[YS];  // per-block col d2 mins (uint bits)

    const int tid   = threadIdx.x;
    const int lane  = tid & 63;
    const int wave  = tid >> 6;
    const int q     = lane >> 5;
    const int n     = lane & 31;
    const int ybase = blockIdx.y * YS;

    // ---- stage y: bf16-split B fragments + colbuf init ----
#pragma unroll
    for (int p = 0; p < 4; ++p) {
        int yloc = tid + p * 256;
        int yi   = ybase + yloc;
        float a = gt[3 * yi + 0], b = gt[3 * yi + 1], c = gt[3 * yi + 2];
        float hy = 0.5f * (a * a + b * b + c * c);
        unsigned short h0 = bf_rne(a), h1 = bf_rne(b), h2 = bf_rne(c);
        unsigned short l0 = bf_rne(a - bf2f(h0));
        unsigned short l1 = bf_rne(b - bf2f(h1));
        unsigned short l2 = bf_rne(c - bf2f(h2));
        unsigned short hh = bf_rne(hy);
        unsigned short hl = bf_rne(hy - bf2f(hh));
        unsigned short nhh = hh ^ 0x8000u, nhl = hl ^ 0x8000u;
        // q0 k0..7: yh0,yh1,yh2, yh0,yh1,yh2, yl0,yl1
        ybufA[yloc] = make_uint4(
            (unsigned)h0 | ((unsigned)h1 << 16),
            (unsigned)h2 | ((unsigned)h0 << 16),
            (unsigned)h1 | ((unsigned)h2 << 16),
            (unsigned)l0 | ((unsigned)l1 << 16));
        // q1 k8..15: yl2, 1, 1, -hyh, -hyl, 0,0,0
        ybufB[yloc] = make_uint4(
            (unsigned)l2 | (ONEBF << 16),
            ONEBF | ((unsigned)nhh << 16),
            (unsigned)nhl,
            0u);
        colbuf[yloc] = 0xFFFFFFFFu;
    }

    // ---- build A fragment (x side, fixed per wave) ----
    const int xt = blockIdx.x * 4 + wave;   // x-tile (32 points)
    const int xi = xt * 32 + n;
    FragAB A;
    {
        float a = pred[3 * xi + 0], b = pred[3 * xi + 1], c = pred[3 * xi + 2];
        float hx = 0.5f * (a * a + b * b + c * c);
        unsigned short h0 = bf_rne(a), h1 = bf_rne(b), h2 = bf_rne(c);
        unsigned short l0 = bf_rne(a - bf2f(h0));
        unsigned short l1 = bf_rne(b - bf2f(h1));
        unsigned short l2 = bf_rne(c - bf2f(h2));
        unsigned short hh = bf_rne(hx);
        unsigned short hl = bf_rne(hx - bf2f(hh));
        unsigned short nhh = hh ^ 0x8000u, nhl = hl ^ 0x8000u;
        if (q == 0) {  // k0..7: xh0,xh1,xh2, xl0,xl1,xl2, xh0,xh1
            A.us[0] = h0; A.us[1] = h1; A.us[2] = h2;
            A.us[3] = l0; A.us[4] = l1; A.us[5] = l2;
            A.us[6] = h0; A.us[7] = h1;
        } else {       // k8..15: xh2, -hxh, -hxl, 1, 1, 0,0,0
            A.us[0] = h2; A.us[1] = nhh; A.us[2] = nhl;
            A.us[3] = (unsigned short)ONEBF; A.us[4] = (unsigned short)ONEBF;
            A.us[5] = 0; A.us[6] = 0; A.us[7] = 0;
        }
    }

    float rmx[16];
#pragma unroll
    for (int r = 0; r < 16; ++r) rmx[r] = -3.0e38f;

    __syncthreads();

    const uint4* __restrict__ ybq = q ? ybufB : ybufA;

    // ---- main loop: 32 y-tiles of 32 ----
    for (int i = 0; i < 32; ++i) {
        FragAB B;
        B.u4 = ybq[i * 32 + n];           // ds_read_b128, contiguous 16B/lane
        FragC D;
        float16 zc = {};
        D.v = __builtin_amdgcn_mfma_f32_32x32x16_bf16(A.s8, B.s8, zc, 0, 0, 0);
#pragma unroll
        for (int r = 0; r < 16; ++r) rmx[r] = fmaxf(rmx[r], D.f[r]);
        // col-max over this lane's 16 rows (max3 tree)
        float t0 = fmaxf(fmaxf(D.f[0],  D.f[1]),  D.f[2]);
        float t1 = fmaxf(fmaxf(D.f[3],  D.f[4]),  D.f[5]);
        float t2 = fmaxf(fmaxf(D.f[6],  D.f[7]),  D.f[8]);
        float t3 = fmaxf(fmaxf(D.f[9],  D.f[10]), D.f[11]);
        float t4 = fmaxf(fmaxf(D.f[12], D.f[13]), D.f[14]);
        float m  = fmaxf(fmaxf(fmaxf(t0, t1), t2),
                         fmaxf(fmaxf(t3, t4), D.f[15]));
        float d2c = fmaxf(-2.0f * m, 0.0f);     // clamp before uint ordering
        // both q-halves atomically combine (same address, 2 lanes/addr)
        atomicMin(&colbuf[i * 32 + n], __float_as_uint(d2c));
    }

    // ---- row side: reduce rmx across the 32 col-lanes, flush to global ----
#pragma unroll
    for (int r = 0; r < 16; ++r) {
        float v = rmx[r];
        v = fmaxf(v, __shfl_xor(v, 1, 64));
        v = fmaxf(v, __shfl_xor(v, 2, 64));
        v = fmaxf(v, __shfl_xor(v, 4, 64));
        v = fmaxf(v, __shfl_xor(v, 8, 64));
        v = fmaxf(v, __shfl_xor(v, 16, 64));
        if (n == 0) {   // lanes 0 (q0) and 32 (q1)
            int row = (r & 3) + 8 * (r >> 2) + 4 * q;
            float d2 = fmaxf(-2.0f * v, 0.0f);
            atomicMin(&minp[xt * 32 + row], __float_as_uint(d2));
        }
    }

    __syncthreads();
    // ---- flush col mins (block-local partials) to global ----
#pragma unroll
    for (int p = 0; p < 4; ++p) {
        int yloc = tid + p * 256;
        atomicMin(&ming[ybase + yloc], colbuf[yloc]);
    }
}

__global__ __launch_bounds__(256) void chamfer_reduce(
        const unsigned int* __restrict__ mins, float* __restrict__ out) {
    const int gid = blockIdx.x * 256 + threadIdx.x;  // 64 blocks x 256
    float s = 0.0f;
#pragma unroll
    for (int i = 0; i < 2; ++i)
        s += sqrtf(__uint_as_float(mins[gid + i * 64 * 256]));
#pragma unroll
    for (int off = 32; off > 0; off >>= 1)
        s += __shfl_down(s, off, 64);
    if ((threadIdx.x & 63) == 0)
        atomicAdd(out, s * (1.0f / (float)NPTS));
}

// ---------------- fallback (tiny ws): R3-style atomic path ----------------

#define FB_RPT  8
#define FB_YSEG 128

__global__ __launch_bounds__(256) void init_mins(unsigned int* mins, float* out) {
    int i = blockIdx.x * blockDim.x + threadIdx.x;
    if (i < 2 * NPTS) mins[i] = 0x7F800000u;
    if (i == 0) out[0] = 0.0f;
}

__global__ __launch_bounds__(256, 4) void chamfer_min_atomic(
        const float* __restrict__ pred, const float* __restrict__ gt,
        unsigned int* __restrict__ mins) {
    const int xb  = blockIdx.x;
    const int ys  = blockIdx.y;
    const int dir = blockIdx.z;
    const float* __restrict__ X = dir ? gt : pred;
    const float* __restrict__ Y = dir ? pred : gt;
    unsigned int* __restrict__ outm = mins + dir * NPTS;
    const int tid = threadIdx.x;

    __shared__ float4 sh[FB_YSEG];
    if (tid < FB_YSEG) {
        int yi = ys * FB_YSEG + tid;
        float a = Y[3 * yi + 0], b = Y[3 * yi + 1], c = Y[3 * yi + 2];
        sh[tid] = make_float4(a, b, c, -0.5f * (a * a + b * b + c * c));
    }
    float xx[FB_RPT], xy[FB_RPT], xz[FB_RPT], x2[FB_RPT], mx[FB_RPT];
    const int xbase = xb * (FB_RPT * 256);
#pragma unroll
    for (int r = 0; r < FB_RPT; ++r) {
        int xi2 = xbase + r * 256 + tid;
        xx[r] = X[3 * xi2 + 0];
        xy[r] = X[3 * xi2 + 1];
        xz[r] = X[3 * xi2 + 2];
        x2[r] = xx[r] * xx[r] + xy[r] * xy[r] + xz[r] * xz[r];
        mx[r] = -3.0e38f;
    }
    __syncthreads();
#pragma unroll 2
    for (int j = 0; j < FB_YSEG; j += 2) {
        float4 y0 = sh[j], y1 = sh[j + 1];
#pragma unroll
        for (int r = 0; r < FB_RPT; ++r) {
            float t0 = fmaf(xz[r], y0.z, y0.w);
            t0 = fmaf(xy[r], y0.y, t0);
            t0 = fmaf(xx[r], y0.x, t0);
            float t1 = fmaf(xz[r], y1.z, y1.w);
            t1 = fmaf(xy[r], y1.y, t1);
            t1 = fmaf(xx[r], y1.x, t1);
            mx[r] = fmaxf(mx[r], fmaxf(t0, t1));
        }
    }
#pragma unroll
    for (int r = 0; r < FB_RPT; ++r) {
        int xi2 = xbase + r * 256 + tid;
        float d2 = fmaxf(fmaf(-2.0f, mx[r], x2[r]), 0.0f);
        atomicMin(&outm[xi2], __float_as_uint(d2));
    }
}

extern "C" void kernel_launch(void* const* d_in, const int* in_sizes, int n_in,
                              void* d_out, int out_size, void* d_ws, size_t ws_size,
                              hipStream_t stream) {
    const float* pred = (const float*)d_in[0];
    const float* gt   = (const float*)d_in[1];
    float* out        = (float*)d_out;
    unsigned int* minp = (unsigned int*)d_ws;   // [NPTS] pred->gt d2 bits
    unsigned int* ming = minp + NPTS;           // [NPTS] gt->pred d2 bits

    if (ws_size >= (size_t)WS_NEED) {
        hipMemsetAsync(d_ws, 0xFF, (size_t)WS_NEED, stream);   // mins = max
        hipMemsetAsync(d_out, 0, sizeof(float), stream);       // out = 0
        hipLaunchKernelGGL(chamfer_mfma, dim3(NXG, NYS), dim3(256), 0, stream,
                           pred, gt, minp, ming);
        hipLaunchKernelGGL(chamfer_reduce, dim3(64), dim3(256), 0, stream,
                           minp, out);
    } else {
        hipLaunchKernelGGL(init_mins, dim3((2 * NPTS + 255) / 256), dim3(256), 0,
                           stream, minp, out);
        hipLaunchKernelGGL(chamfer_min_atomic, dim3(NPTS / (FB_RPT * 256),
                           NPTS / FB_YSEG, 2), dim3(256), 0, stream,
                           pred, gt, minp);
        hipLaunchKernelGGL(chamfer_reduce, dim3(64), dim3(256), 0, stream,
                           minp, out);
    }
}